// Round 9
// baseline (204.633 us; speedup 1.0000x reference)
//
#include <hip/hip_runtime.h>
#include <hip/hip_bf16.h>
#include <math.h>

#define NH   12
#define HD   64
#define HID  768
#define NB   4
#define SS   2048
#define MR   (NB*SS)   // 8192 rows

#define NXE  (MR*HID)        // x elems        6291456
#define NWE  (HID*HID)       // one W elems     589824

typedef unsigned short u16;
typedef u16   u16x8  __attribute__((ext_vector_type(8)));
typedef __bf16 bf16x8 __attribute__((ext_vector_type(8)));
typedef float f32x4  __attribute__((ext_vector_type(4)));

__device__ __forceinline__ u16 f2b(float f) {
    union { float f; unsigned i; } c; c.f = f;
    unsigned x = c.i + 0x7fffu + ((c.i >> 16) & 1u);   // RNE
    return (u16)(x >> 16);
}
__device__ __forceinline__ unsigned pk2(float lo, float hi) {
    float2 f; f.x = lo; f.y = hi;
    union { __hip_bfloat162 h; unsigned u; } c;
    c.h = __float22bfloat162_rn(f);
    return c.u;
}
__device__ __forceinline__ f32x4 mfma16(u16x8 a, u16x8 b, f32x4 c) {
    return __builtin_amdgcn_mfma_f32_16x16x32_bf16(
        __builtin_bit_cast(bf16x8, a), __builtin_bit_cast(bf16x8, b), c, 0, 0, 0);
}
__device__ __forceinline__ void g2l16(const u16* g, u16* l) {
    __builtin_amdgcn_global_load_lds(
        (const __attribute__((address_space(1))) void*)g,
        (__attribute__((address_space(3))) void*)l, 16, 0, 0);
}
// pi: stored-row permutation for K (inverse of fragment key map g)
__device__ __forceinline__ int kperm(int k) {
    return ((k >> 5) << 5) | (((k >> 2) & 1) << 4) | (((k >> 3) & 3) << 2) | (k & 3);
}

// LDS tile swizzle (T2): tiles are [rows][32] u16 (64B rows, 4x16B slots).
// Slot index is XOR'd with (row>>1)&3 so row bits land in bank bits [3:2].
// global_load_lds writes linearly, so the swizzle is applied by permuting the
// per-lane GLOBAL source slot (staging) and the read slot (fragments) with the
// same involution (rule #21: both-sides-or-neither).
// Verified R1: SQ_LDS_BANK_CONFLICT 6.29M -> 0.

// -------- one-time fp32 -> bf16 conversion of x and the three W matrices ----
__global__ __launch_bounds__(256) void to_bf16(
    const float* __restrict__ x,  const float* __restrict__ Wq,
    const float* __restrict__ Wk, const float* __restrict__ Wv,
    u16* __restrict__ dst)
{
    const int NX4 = NXE / 4, NW4 = NWE / 4, NT4 = NX4 + 3 * NW4;
    for (int i = blockIdx.x * 256 + threadIdx.x; i < NT4; i += gridDim.x * 256) {
        const float* src; u16* d;
        if (i < NX4) { src = x + (size_t)i * 4; d = dst + (size_t)i * 4; }
        else {
            int j = i - NX4; int w = j / NW4; int r = j - w * NW4;
            const float* Ws = (w == 0) ? Wq : ((w == 1) ? Wk : Wv);
            src = Ws + (size_t)r * 4; d = dst + NXE + (size_t)w * NWE + (size_t)r * 4;
        }
        float4 f = *(const float4*)src;
        uint2 o; o.x = pk2(f.x, f.y); o.y = pk2(f.z, f.w);
        *(uint2*)d = o;
    }
}

// -------- QKV projection: 128x128 tile, BK=64 via dual pitch-32 sub-tiles ---
// Main loop = R1 version (frozen). Q/K epilogue via per-wave Lt LDS bounce
// (R7, measured neutral-to-slightly-better; kept). V transposed [b,h][d][s].
__global__ __launch_bounds__(256, 3) void qkv_proj(
    const u16* __restrict__ xb, const u16* __restrict__ Wb,
    const float* __restrict__ bq, const float* __restrict__ bk,
    const float* __restrict__ bv, u16* __restrict__ qkv)
{
    const int wsel = blockIdx.z;
    const u16* W = Wb + (size_t)wsel * NWE;
    const float* bias = (wsel == 0) ? bq : ((wsel == 1) ? bk : bv);
    u16* out = qkv + (size_t)wsel * MR * HID;

    const int m0 = blockIdx.x * 128, n0 = blockIdx.y * 128;
    __shared__ __align__(16) u16 smem[18432];

    const int tid  = threadIdx.x;
    const int lane = tid & 63, wid = tid >> 6;
    const int quad = lane >> 4, l16 = lane & 15;
    const int wm = wid >> 1, wn = wid & 1;
    const int qsw = quad ^ ((l16 >> 1) & 3);            // swizzled read slot

    const int rA = 2 * wid * 16 + (lane >> 2);
    const int colh = 8 * ((lane & 3) ^ ((lane >> 3) & 3));   // swizzled src slot
    const u16* gx0 = xb + (size_t)(m0 + rA) * HID + colh;
    const u16* gx1 = gx0 + (size_t)16 * HID;
    const u16* gw0 = W  + (size_t)(n0 + rA) * HID + colh;
    const u16* gw1 = gw0 + (size_t)16 * HID;
    u16* lA = smem + (2 * wid) * 512 + lane * 8;

    f32x4 acc[4][4] = {};

    for (int k0 = 0; k0 < HID; k0 += 64) {
        g2l16(gx0 + k0,      lA);            g2l16(gx1 + k0,      lA + 512);
        g2l16(gx0 + k0 + 32, lA + 4096);     g2l16(gx1 + k0 + 32, lA + 4608);
        g2l16(gw0 + k0,      lA + 8192);     g2l16(gw1 + k0,      lA + 8704);
        g2l16(gw0 + k0 + 32, lA + 12288);    g2l16(gw1 + k0 + 32, lA + 12800);
        __syncthreads();
        #pragma unroll
        for (int hh = 0; hh < 2; hh++) {
            u16x8 af[4], bf[4];
            #pragma unroll
            for (int i = 0; i < 4; i++)
                af[i] = *(const u16x8*)(smem + hh * 4096 + (wm * 64 + i * 16 + l16) * 32 + qsw * 8);
            #pragma unroll
            for (int j = 0; j < 4; j++)
                bf[j] = *(const u16x8*)(smem + 8192 + hh * 4096 + (wn * 64 + j * 16 + l16) * 32 + qsw * 8);
            #pragma unroll
            for (int i = 0; i < 4; i++)
                #pragma unroll
                for (int j = 0; j < 4; j++)
                    acc[i][j] = mfma16(af[i], bf[j], acc[i][j]);
        }
        __syncthreads();
    }

    u16* lt = smem + wid * 4608;   // per-wave [64][72]

    if (wsel == 2) {
        #pragma unroll
        for (int j = 0; j < 4; j++) {
            const int col = n0 + wn * 64 + j * 16 + l16;
            const float bb = bias[col];
            #pragma unroll
            for (int i = 0; i < 4; i++) {
                uint2 pk;
                pk.x = pk2(acc[i][j][0] + bb, acc[i][j][1] + bb);
                pk.y = pk2(acc[i][j][2] + bb, acc[i][j][3] + bb);
                *(uint2*)(lt + (j * 16 + l16) * 72 + i * 16 + quad * 4) = pk;
            }
        }
        __syncthreads();
        const int bidx = m0 >> 11;
        const int s0 = (m0 & 2047) + wm * 64;
        #pragma unroll
        for (int it = 0; it < 8; it++) {
            const int dl = it * 8 + (lane >> 3), sl = (lane & 7) * 8;
            uint4 w = *(const uint4*)(lt + dl * 72 + sl);
            const int col = n0 + wn * 64 + dl;
            const int hh = col >> 6, d = col & 63;
            *(uint4*)(out + ((size_t)(bidx * NH + hh) * HD + d) * SS + s0 + sl) = w;
        }
    } else {
        const float scale = (wsel == 0) ? 0.18033688f : 1.0f;   // 0.125/ln2 for Q
        #pragma unroll
        for (int j = 0; j < 4; j++) {
            const int col = n0 + wn * 64 + j * 16 + l16;
            const float bb = bias[col];
            #pragma unroll
            for (int i = 0; i < 4; i++)
                #pragma unroll
                for (int r = 0; r < 4; r++)
                    lt[(i * 16 + quad * 4 + r) * 72 + j * 16 + l16] =
                        f2b((acc[i][j][r] + bb) * scale);
        }
        __syncthreads();
        const size_t rowbase = (size_t)(m0 + wm * 64);
        const int cb = n0 + wn * 64;
        #pragma unroll
        for (int it = 0; it < 8; it++) {
            const int dl = it * 8 + (lane >> 3), sl = (lane & 7) * 8;
            uint4 w = *(const uint4*)(lt + dl * 72 + sl);
            const int grow = (wsel == 1) ? kperm(dl) : dl;
            *(uint4*)(out + (rowbase + grow) * HID + cb + sl) = w;
        }
    }
}

// -------- Flash attention: 2x2 wave split (q-half x key-half) --------------
// R4/R6 synthesis: the binding resource is LDS fragment delivery -- with a
// q-only wave split, each of 4 waves reads the FULL K+V tile (16KB/wave/iter,
// 4x duplication; per-CU-iter LDS ~2300cy >= MFMA ~2100cy). R4 doubled
// LDS-per-MFMA and lost 17%; this HALVES it: wave (wq,wk) = 64 q-rows x 32
// keys -> kf 4 + vf 4 = 8 b128/wave/iter. MFMA count/wave unchanged (16 QK +
// 4 denom + 16 PV), exp unchanged (32/lane). PV is linear over keys: each
// wave accumulates partial o2/lacc over its key-half; ONE end-of-kernel
// cross-wave add (wk=1 dumps to dead KS/VS, wk=0 adds + writes out).
// Ring-3 counted-vmcnt discipline, staging, T2 swizzle: byte-identical to R2.
// VGPR ~150 expected (tripwire: FETCH_SIZE >> 18.5MB = spill = revert).
__global__ __launch_bounds__(256, 3) void attn(
    const u16* __restrict__ qkv, float* __restrict__ out)
{
    const int lin = blockIdx.x;          // 0..767
    const int rx  = lin & 7;             // XCD residue
    const int gg  = lin >> 3;            // 0..95
    const int qt  = gg & 15;
    const int bh  = rx * 6 + (gg >> 4);  // 0..47
    const int b   = bh / NH, h = bh - b * NH;
    const int q0  = qt * 128;

    const u16* qb  = qkv + (size_t)b * SS * HID + h * HD;
    const u16* kb  = qkv + (size_t)MR * HID + (size_t)b * SS * HID + h * HD;
    const u16* vtb = qkv + (size_t)2 * MR * HID + ((size_t)(b * NH + h) * HD) * SS;
    float*     ob  = out + (size_t)b * SS * HID + h * HD;

    // ring-3: [buf][hh][64 rows][32 cols]; 24 KB K + 24 KB V -> 3 blocks/CU
    __shared__ __align__(16) u16 KS[3][2][2048];
    __shared__ __align__(16) u16 VS[3][2][2048];

    const int tid  = threadIdx.x;
    const int lane = tid & 63, wid = tid >> 6;
    const int quad = lane >> 4, l16 = lane & 15;
    const int qsw = quad ^ ((l16 >> 1) & 3);            // swizzled read slot
    const int wq = wid >> 1;             // q-half: rows q0 + wq*64 + t*16
    const int wk = wid & 1;              // key-half: keys wk*32 + n*16

    // staging addresses: wave w -> rows 16w..16w+15 of each sub-tile
    const int srow = 16 * wid + (lane >> 2);
    const int sc8  = 8 * ((lane & 3) ^ ((lane >> 3) & 3));   // swizzled src slot
    const int ldst = wid * 512 + lane * 8;

    const u16* kg = kb + (size_t)srow * HID + sc8;
    const u16* vg = vtb + (size_t)srow * SS + sc8;

#define ASTAGE(kt, bf_) do {                                            \
        const u16* k_ = kg + (size_t)(kt) * 64 * HID;                   \
        const u16* v_ = vg + (kt) * 64;                                 \
        g2l16(k_,      &KS[(bf_)][0][0] + ldst);                        \
        g2l16(k_ + 32, &KS[(bf_)][1][0] + ldst);                        \
        g2l16(v_,      &VS[(bf_)][0][0] + ldst);                        \
        g2l16(v_ + 32, &VS[(bf_)][1][0] + ldst);                        \
    } while (0)

    u16x8 qf[4][2];
    #pragma unroll
    for (int t = 0; t < 4; t++) {
        const int row = q0 + wq * 64 + t * 16 + l16;
        #pragma unroll
        for (int hh = 0; hh < 2; hh++)
            qf[t][hh] = *(const u16x8*)(qb + (size_t)row * HID + hh * 32 + quad * 8);
    }

    u16x8 ones;
    #pragma unroll
    for (int e = 0; e < 8; e++) ones[e] = 0x3F80;   // bf16 1.0

    f32x4 o2[4][4] = {};
    f32x4 lacc[4] = {};

    ASTAGE(0, 0);
    ASTAGE(1, 1);

    for (int kt = 0; kt < SS / 64; kt++) {
        const int cur = kt % 3, nb = (kt + 2) % 3;

        if (kt < 31) asm volatile("s_waitcnt vmcnt(4)" ::: "memory");
        else         asm volatile("s_waitcnt vmcnt(0)" ::: "memory");
        __builtin_amdgcn_s_barrier();
        if (kt + 2 < 32) ASTAGE(kt + 2, nb);

        const u16* ksb = &KS[cur][0][0];
        const u16* vsb = &VS[cur][0][0];

        // this wave's key-half only: 4 + 4 b128 reads (halved vs q-only split)
        u16x8 kf[2][2];
        #pragma unroll
        for (int n = 0; n < 2; n++)
            #pragma unroll
            for (int hh = 0; hh < 2; hh++)
                kf[n][hh] = *(const u16x8*)(ksb + hh * 2048 + (wk * 32 + n * 16 + l16) * 32 + qsw * 8);

        u16x8 vf[4];
        #pragma unroll
        for (int n2 = 0; n2 < 4; n2++)
            vf[n2] = *(const u16x8*)(vsb + wk * 2048 + (n2 * 16 + l16) * 32 + qsw * 8);

        unsigned pkd[4][2][2];
        __builtin_amdgcn_s_setprio(1);
        #pragma unroll
        for (int t = 0; t < 4; t++)
            #pragma unroll
            for (int n = 0; n < 2; n++) {
                f32x4 s = {-6.f, -6.f, -6.f, -6.f};   // fixed softmax shift
                s = mfma16(kf[n][0], qf[t][0], s);
                s = mfma16(kf[n][1], qf[t][1], s);
                const float p0 = __builtin_amdgcn_exp2f(s[0]);
                const float p1 = __builtin_amdgcn_exp2f(s[1]);
                const float p2 = __builtin_amdgcn_exp2f(s[2]);
                const float p3 = __builtin_amdgcn_exp2f(s[3]);
                pkd[t][n][0] = pk2(p0, p1);
                pkd[t][n][1] = pk2(p2, p3);
            }
        __builtin_amdgcn_s_setprio(0);

        __builtin_amdgcn_s_setprio(1);
        #pragma unroll
        for (int t = 0; t < 4; t++) {
            union { u16x8 v; unsigned d[4]; } bf;
            bf.d[0] = pkd[t][0][0]; bf.d[1] = pkd[t][0][1];
            bf.d[2] = pkd[t][1][0]; bf.d[3] = pkd[t][1][1];
            lacc[t] = mfma16(ones, bf.v, lacc[t]);   // partial denom (32 keys)
            #pragma unroll
            for (int n2 = 0; n2 < 4; n2++)
                o2[t][n2] = mfma16(vf[n2], bf.v, o2[t][n2]);
        }
        __builtin_amdgcn_s_setprio(0);
    }
#undef ASTAGE

    // cross-wave reduction over key-halves: wk=1 dumps (o2, lacc) into the
    // dead staging buffers (stride-84 to spread banks), wk=0 adds + writes.
    __syncthreads();
    {
        float* red = (wq == 0) ? (float*)&KS[0][0][0] : (float*)&VS[0][0][0];
        float* p = red + lane * 84;
        if (wk == 1) {
            #pragma unroll
            for (int t = 0; t < 4; t++) {
                #pragma unroll
                for (int n2 = 0; n2 < 4; n2++)
                    *(f32x4*)(p + (t * 4 + n2) * 4) = o2[t][n2];
                *(f32x4*)(p + 64 + t * 4) = lacc[t];
            }
        }
        __syncthreads();
        if (wk == 0) {
            #pragma unroll
            for (int t = 0; t < 4; t++) {
                #pragma unroll
                for (int n2 = 0; n2 < 4; n2++)
                    o2[t][n2] += *(const f32x4*)(p + (t * 4 + n2) * 4);
                lacc[t] += *(const f32x4*)(p + 64 + t * 4);
            }
            #pragma unroll
            for (int t = 0; t < 4; t++) {
                const float inv = 1.f / lacc[t][0];   // colsum for q=l16
                const int q = q0 + wq * 64 + t * 16 + l16;
                #pragma unroll
                for (int n2 = 0; n2 < 4; n2++) {
                    f32x4 w = o2[t][n2];
                    w[0] *= inv; w[1] *= inv; w[2] *= inv; w[3] *= inv;
                    *(f32x4*)(ob + (size_t)q * HID + n2 * 16 + quad * 4) = w;
                }
            }
        }
    }
}

extern "C" void kernel_launch(void* const* d_in, const int* in_sizes, int n_in,
                              void* d_out, int out_size, void* d_ws, size_t ws_size,
                              hipStream_t stream) {
    const float* x  = (const float*)d_in[0];
    const float* Wq = (const float*)d_in[1];
    const float* bq = (const float*)d_in[2];
    const float* Wk = (const float*)d_in[3];
    const float* bk = (const float*)d_in[4];
    const float* Wv = (const float*)d_in[5];
    const float* bv = (const float*)d_in[6];
    float* out = (float*)d_out;
    u16* qkv = (u16*)d_ws;               // 36 MB scratch: Q | K(perm) | V^T
    u16* cvt = (u16*)d_out;              // bf16 x|Wq|Wk|Wv staged in output buf

    to_bf16<<<1024, 256, 0, stream>>>(x, Wq, Wk, Wv, cvt);

    dim3 gp(MR / 128, HID / 128, 3);    // 64 x 6 x 3
    qkv_proj<<<gp, 256, 0, stream>>>(cvt, cvt + NXE, bq, bk, bv, qkv);

    attn<<<768, 256, 0, stream>>>(qkv, out);   // 1D, XCD-swizzled
}

// Round 10
// 179.335 us; speedup vs baseline: 1.1411x; 1.1411x over previous
//
#include <hip/hip_runtime.h>
#include <hip/hip_bf16.h>
#include <math.h>

#define NH   12
#define HD   64
#define HID  768
#define NB   4
#define SS   2048
#define MR   (NB*SS)   // 8192 rows

#define NXE  (MR*HID)        // x elems        6291456
#define NWE  (HID*HID)       // one W elems     589824

typedef unsigned short u16;
typedef u16   u16x8  __attribute__((ext_vector_type(8)));
typedef __bf16 bf16x8 __attribute__((ext_vector_type(8)));
typedef float f32x4  __attribute__((ext_vector_type(4)));

__device__ __forceinline__ u16 f2b(float f) {
    union { float f; unsigned i; } c; c.f = f;
    unsigned x = c.i + 0x7fffu + ((c.i >> 16) & 1u);   // RNE
    return (u16)(x >> 16);
}
__device__ __forceinline__ unsigned pk2(float lo, float hi) {
    float2 f; f.x = lo; f.y = hi;
    union { __hip_bfloat162 h; unsigned u; } c;
    c.h = __float22bfloat162_rn(f);
    return c.u;
}
__device__ __forceinline__ f32x4 mfma16(u16x8 a, u16x8 b, f32x4 c) {
    return __builtin_amdgcn_mfma_f32_16x16x32_bf16(
        __builtin_bit_cast(bf16x8, a), __builtin_bit_cast(bf16x8, b), c, 0, 0, 0);
}
__device__ __forceinline__ void g2l16(const u16* g, u16* l) {
    __builtin_amdgcn_global_load_lds(
        (const __attribute__((address_space(1))) void*)g,
        (__attribute__((address_space(3))) void*)l, 16, 0, 0);
}
// pi: stored-row permutation for K (inverse of fragment key map g)
__device__ __forceinline__ int kperm(int k) {
    return ((k >> 5) << 5) | (((k >> 2) & 1) << 4) | (((k >> 3) & 3) << 2) | (k & 3);
}

// LDS tile swizzle (T2): tiles are [rows][32] u16 (64B rows, 4x16B slots).
// Slot index is XOR'd with (row>>1)&3 so row bits land in bank bits [3:2].
// global_load_lds writes linearly, so the swizzle is applied by permuting the
// per-lane GLOBAL source slot (staging) and the read slot (fragments) with the
// same involution (rule #21: both-sides-or-neither).
// Verified R1: SQ_LDS_BANK_CONFLICT 6.29M -> 0.

// -------- one-time fp32 -> bf16 conversion of x and the three W matrices ----
__global__ __launch_bounds__(256) void to_bf16(
    const float* __restrict__ x,  const float* __restrict__ Wq,
    const float* __restrict__ Wk, const float* __restrict__ Wv,
    u16* __restrict__ dst)
{
    const int NX4 = NXE / 4, NW4 = NWE / 4, NT4 = NX4 + 3 * NW4;
    for (int i = blockIdx.x * 256 + threadIdx.x; i < NT4; i += gridDim.x * 256) {
        const float* src; u16* d;
        if (i < NX4) { src = x + (size_t)i * 4; d = dst + (size_t)i * 4; }
        else {
            int j = i - NX4; int w = j / NW4; int r = j - w * NW4;
            const float* Ws = (w == 0) ? Wq : ((w == 1) ? Wk : Wv);
            src = Ws + (size_t)r * 4; d = dst + NXE + (size_t)w * NWE + (size_t)r * 4;
        }
        float4 f = *(const float4*)src;
        uint2 o; o.x = pk2(f.x, f.y); o.y = pk2(f.z, f.w);
        *(uint2*)d = o;
    }
}

// -------- QKV projection: 128x128 tile, BK=64 via dual pitch-32 sub-tiles ---
// Main loop = R1 version (frozen); Q/K epilogue Lt bounce (R7).
// NEW (R10): XCD-aware 1D grid (T1). Default round-robin scatters the 18x
// re-read of x (6 n-tiles x 3 wsel, 442 MB total staging) across all 8 L2s
// -> L3-served. Remap: lin&7 = XCD; each XCD owns 8 m-tiles (x-chunk 1024
// rows = 1.5 MB, L2-resident) x all 18 (n0,wsel) combos (W panel 192 KB).
// x staging then hits local L2 (~34 TB/s) instead of L3. Body untouched.
__global__ __launch_bounds__(256, 3) void qkv_proj(
    const u16* __restrict__ xb, const u16* __restrict__ Wb,
    const float* __restrict__ bq, const float* __restrict__ bk,
    const float* __restrict__ bv, u16* __restrict__ qkv)
{
    const int lin = blockIdx.x;          // 0..1151
    const int rx  = lin & 7;             // XCD residue
    const int g   = lin >> 3;            // 0..143
    const int mt  = g & 7;               // m-tile within this XCD's chunk
    const int c   = g >> 3;              // 0..17 = (wsel, n-tile) combo
    const int wsel = c / 6;
    const int n0  = (c - wsel * 6) * 128;
    const int m0  = (rx * 8 + mt) * 128;

    const u16* W = Wb + (size_t)wsel * NWE;
    const float* bias = (wsel == 0) ? bq : ((wsel == 1) ? bk : bv);
    u16* out = qkv + (size_t)wsel * MR * HID;

    __shared__ __align__(16) u16 smem[18432];

    const int tid  = threadIdx.x;
    const int lane = tid & 63, wid = tid >> 6;
    const int quad = lane >> 4, l16 = lane & 15;
    const int wm = wid >> 1, wn = wid & 1;
    const int qsw = quad ^ ((l16 >> 1) & 3);            // swizzled read slot

    const int rA = 2 * wid * 16 + (lane >> 2);
    const int colh = 8 * ((lane & 3) ^ ((lane >> 3) & 3));   // swizzled src slot
    const u16* gx0 = xb + (size_t)(m0 + rA) * HID + colh;
    const u16* gx1 = gx0 + (size_t)16 * HID;
    const u16* gw0 = W  + (size_t)(n0 + rA) * HID + colh;
    const u16* gw1 = gw0 + (size_t)16 * HID;
    u16* lA = smem + (2 * wid) * 512 + lane * 8;

    f32x4 acc[4][4] = {};

    for (int k0 = 0; k0 < HID; k0 += 64) {
        g2l16(gx0 + k0,      lA);            g2l16(gx1 + k0,      lA + 512);
        g2l16(gx0 + k0 + 32, lA + 4096);     g2l16(gx1 + k0 + 32, lA + 4608);
        g2l16(gw0 + k0,      lA + 8192);     g2l16(gw1 + k0,      lA + 8704);
        g2l16(gw0 + k0 + 32, lA + 12288);    g2l16(gw1 + k0 + 32, lA + 12800);
        __syncthreads();
        #pragma unroll
        for (int hh = 0; hh < 2; hh++) {
            u16x8 af[4], bf[4];
            #pragma unroll
            for (int i = 0; i < 4; i++)
                af[i] = *(const u16x8*)(smem + hh * 4096 + (wm * 64 + i * 16 + l16) * 32 + qsw * 8);
            #pragma unroll
            for (int j = 0; j < 4; j++)
                bf[j] = *(const u16x8*)(smem + 8192 + hh * 4096 + (wn * 64 + j * 16 + l16) * 32 + qsw * 8);
            #pragma unroll
            for (int i = 0; i < 4; i++)
                #pragma unroll
                for (int j = 0; j < 4; j++)
                    acc[i][j] = mfma16(af[i], bf[j], acc[i][j]);
        }
        __syncthreads();
    }

    u16* lt = smem + wid * 4608;   // per-wave [64][72]

    if (wsel == 2) {
        #pragma unroll
        for (int j = 0; j < 4; j++) {
            const int col = n0 + wn * 64 + j * 16 + l16;
            const float bb = bias[col];
            #pragma unroll
            for (int i = 0; i < 4; i++) {
                uint2 pk;
                pk.x = pk2(acc[i][j][0] + bb, acc[i][j][1] + bb);
                pk.y = pk2(acc[i][j][2] + bb, acc[i][j][3] + bb);
                *(uint2*)(lt + (j * 16 + l16) * 72 + i * 16 + quad * 4) = pk;
            }
        }
        __syncthreads();
        const int bidx = m0 >> 11;
        const int s0 = (m0 & 2047) + wm * 64;
        #pragma unroll
        for (int it = 0; it < 8; it++) {
            const int dl = it * 8 + (lane >> 3), sl = (lane & 7) * 8;
            uint4 w = *(const uint4*)(lt + dl * 72 + sl);
            const int col = n0 + wn * 64 + dl;
            const int hh = col >> 6, d = col & 63;
            *(uint4*)(out + ((size_t)(bidx * NH + hh) * HD + d) * SS + s0 + sl) = w;
        }
    } else {
        const float scale = (wsel == 0) ? 0.18033688f : 1.0f;   // 0.125/ln2 for Q
        #pragma unroll
        for (int j = 0; j < 4; j++) {
            const int col = n0 + wn * 64 + j * 16 + l16;
            const float bb = bias[col];
            #pragma unroll
            for (int i = 0; i < 4; i++)
                #pragma unroll
                for (int r = 0; r < 4; r++)
                    lt[(i * 16 + quad * 4 + r) * 72 + j * 16 + l16] =
                        f2b((acc[i][j][r] + bb) * scale);
        }
        __syncthreads();
        const size_t rowbase = (size_t)(m0 + wm * 64);
        const int cb = n0 + wn * 64;
        #pragma unroll
        for (int it = 0; it < 8; it++) {
            const int dl = it * 8 + (lane >> 3), sl = (lane & 7) * 8;
            uint4 w = *(const uint4*)(lt + dl * 72 + sl);
            const int grow = (wsel == 1) ? kperm(dl) : dl;
            *(uint4*)(out + (rowbase + grow) * HID + cb + sl) = w;
        }
    }
}

// -------- Flash attention: XCD-swizzled grid, counted-vmcnt ring-3 ---------
// R7 version exactly (best measured: 65.7us). Six structural variants (R2-qkv
// style, T15, QBLK=64, V-direct, VALU-denom, 2x2 split) all regressed; the
// 2x2 split (R9) spilled (peak live set ~190 regs > 168 cap). This structure
// is the floor. Ring-3 K/V buffers, prefetch distance 2, s_waitcnt vmcnt(4)
// + raw s_barrier per iter, stage issued AFTER the barrier. Fixed-shift
// softmax (QK acc init -6), denominator via ones-MFMA. LDS XOR-swizzled
// (T2, conflicts==0 R1-verified); setprio (T5) on MFMA.
__global__ __launch_bounds__(256, 3) void attn(
    const u16* __restrict__ qkv, float* __restrict__ out)
{
    const int lin = blockIdx.x;          // 0..767
    const int rx  = lin & 7;             // XCD residue
    const int gg  = lin >> 3;            // 0..95
    const int qt  = gg & 15;
    const int bh  = rx * 6 + (gg >> 4);  // 0..47
    const int b   = bh / NH, h = bh - b * NH;
    const int q0  = qt * 128;

    const u16* qb  = qkv + (size_t)b * SS * HID + h * HD;
    const u16* kb  = qkv + (size_t)MR * HID + (size_t)b * SS * HID + h * HD;
    const u16* vtb = qkv + (size_t)2 * MR * HID + ((size_t)(b * NH + h) * HD) * SS;
    float*     ob  = out + (size_t)b * SS * HID + h * HD;

    // ring-3: [buf][hh][64 rows][32 cols]; 24 KB K + 24 KB V -> 3 blocks/CU
    __shared__ __align__(16) u16 KS[3][2][2048];
    __shared__ __align__(16) u16 VS[3][2][2048];

    const int tid  = threadIdx.x;
    const int lane = tid & 63, wid = tid >> 6;
    const int quad = lane >> 4, l16 = lane & 15;
    const int qsw = quad ^ ((l16 >> 1) & 3);            // swizzled read slot

    // staging addresses: wave w -> rows 16w..16w+15 of each sub-tile
    const int srow = 16 * wid + (lane >> 2);
    const int sc8  = 8 * ((lane & 3) ^ ((lane >> 3) & 3));   // swizzled src slot
    const int ldst = wid * 512 + lane * 8;

    const u16* kg = kb + (size_t)srow * HID + sc8;
    const u16* vg = vtb + (size_t)srow * SS + sc8;

#define ASTAGE(kt, bf_) do {                                            \
        const u16* k_ = kg + (size_t)(kt) * 64 * HID;                   \
        const u16* v_ = vg + (kt) * 64;                                 \
        g2l16(k_,      &KS[(bf_)][0][0] + ldst);                        \
        g2l16(k_ + 32, &KS[(bf_)][1][0] + ldst);                        \
        g2l16(v_,      &VS[(bf_)][0][0] + ldst);                        \
        g2l16(v_ + 32, &VS[(bf_)][1][0] + ldst);                        \
    } while (0)

    u16x8 qf[2][2];
    #pragma unroll
    for (int t = 0; t < 2; t++) {
        const int row = q0 + t * 64 + wid * 16 + l16;
        #pragma unroll
        for (int hh = 0; hh < 2; hh++)
            qf[t][hh] = *(const u16x8*)(qb + (size_t)row * HID + hh * 32 + quad * 8);
    }

    u16x8 ones;
    #pragma unroll
    for (int e = 0; e < 8; e++) ones[e] = 0x3F80;   // bf16 1.0

    f32x4 o2[2][4] = {};
    f32x4 lacc[2] = {};

    ASTAGE(0, 0);
    ASTAGE(1, 1);

    for (int kt = 0; kt < SS / 64; kt++) {
        const int cur = kt % 3, nb = (kt + 2) % 3;

        if (kt < 31) asm volatile("s_waitcnt vmcnt(4)" ::: "memory");
        else         asm volatile("s_waitcnt vmcnt(0)" ::: "memory");
        __builtin_amdgcn_s_barrier();
        if (kt + 2 < 32) ASTAGE(kt + 2, nb);

        const u16* ksb = &KS[cur][0][0];
        const u16* vsb = &VS[cur][0][0];

        u16x8 kf[4][2];
        #pragma unroll
        for (int n = 0; n < 4; n++)
            #pragma unroll
            for (int hh = 0; hh < 2; hh++)
                kf[n][hh] = *(const u16x8*)(ksb + hh * 2048 + (n * 16 + l16) * 32 + qsw * 8);

        unsigned pkd[2][4][2];
        __builtin_amdgcn_s_setprio(1);
        #pragma unroll
        for (int t = 0; t < 2; t++)
            #pragma unroll
            for (int n = 0; n < 4; n++) {
                f32x4 s = {-6.f, -6.f, -6.f, -6.f};   // fixed softmax shift
                s = mfma16(kf[n][0], qf[t][0], s);
                s = mfma16(kf[n][1], qf[t][1], s);
                const float p0 = __builtin_amdgcn_exp2f(s[0]);
                const float p1 = __builtin_amdgcn_exp2f(s[1]);
                const float p2 = __builtin_amdgcn_exp2f(s[2]);
                const float p3 = __builtin_amdgcn_exp2f(s[3]);
                pkd[t][n][0] = pk2(p0, p1);
                pkd[t][n][1] = pk2(p2, p3);
            }
        __builtin_amdgcn_s_setprio(0);

        u16x8 vf[4][2];
        #pragma unroll
        for (int n2 = 0; n2 < 4; n2++)
            #pragma unroll
            for (int hh = 0; hh < 2; hh++)
                vf[n2][hh] = *(const u16x8*)(vsb + hh * 2048 + (n2 * 16 + l16) * 32 + qsw * 8);

        __builtin_amdgcn_s_setprio(1);
        #pragma unroll
        for (int t = 0; t < 2; t++) {
            union { u16x8 v; unsigned d[4]; } bf0, bf1;
            bf0.d[0] = pkd[t][0][0]; bf0.d[1] = pkd[t][0][1];
            bf0.d[2] = pkd[t][1][0]; bf0.d[3] = pkd[t][1][1];
            bf1.d[0] = pkd[t][2][0]; bf1.d[1] = pkd[t][2][1];
            bf1.d[2] = pkd[t][3][0]; bf1.d[3] = pkd[t][3][1];
            lacc[t] = mfma16(ones, bf0.v, lacc[t]);   // denominator colsums
            lacc[t] = mfma16(ones, bf1.v, lacc[t]);
            #pragma unroll
            for (int n2 = 0; n2 < 4; n2++) {
                o2[t][n2] = mfma16(vf[n2][0], bf0.v, o2[t][n2]);
                o2[t][n2] = mfma16(vf[n2][1], bf1.v, o2[t][n2]);
            }
        }
        __builtin_amdgcn_s_setprio(0);
    }
#undef ASTAGE

    #pragma unroll
    for (int t = 0; t < 2; t++) {
        const float inv = 1.f / lacc[t][0];   // all regs hold the q=l16 colsum
        const int q = q0 + t * 64 + wid * 16 + l16;
        #pragma unroll
        for (int n2 = 0; n2 < 4; n2++) {
            f32x4 w = o2[t][n2];
            w[0] *= inv; w[1] *= inv; w[2] *= inv; w[3] *= inv;
            *(f32x4*)(ob + (size_t)q * HID + n2 * 16 + quad * 4) = w;
        }
    }
}

extern "C" void kernel_launch(void* const* d_in, const int* in_sizes, int n_in,
                              void* d_out, int out_size, void* d_ws, size_t ws_size,
                              hipStream_t stream) {
    const float* x  = (const float*)d_in[0];
    const float* Wq = (const float*)d_in[1];
    const float* bq = (const float*)d_in[2];
    const float* Wk = (const float*)d_in[3];
    const float* bk = (const float*)d_in[4];
    const float* Wv = (const float*)d_in[5];
    const float* bv = (const float*)d_in[6];
    float* out = (float*)d_out;
    u16* qkv = (u16*)d_ws;               // 36 MB scratch: Q | K(perm) | V^T
    u16* cvt = (u16*)d_out;              // bf16 x|Wq|Wk|Wv staged in output buf

    to_bf16<<<1024, 256, 0, stream>>>(x, Wq, Wk, Wv, cvt);

    qkv_proj<<<1152, 256, 0, stream>>>(cvt, cvt + NXE, bq, bk, bv, qkv);  // 1D, XCD-swizzled

    attn<<<768, 256, 0, stream>>>(qkv, out);   // 1D, XCD-swizzled
}